// Round 14
// baseline (379.632 us; speedup 1.0000x reference)
//
#include <hip/hip_runtime.h>
#include <hip/hip_bf16.h>

// ---------------------------------------------------------------------------
// Deformable bottleneck. Round 21:
//   - k3 deform loop rewritten: px-slice waves (wave wv owns px wv*16..+16,
//     A-fragment row = lr = px) so the bilinear gather lands DIRECTLY in
//     MFMA A-fragment registers -- colsA and its transpose round trip are
//     deleted. B k-slice staged to one LDS buffer via registers with strict
//     vmcnt-FIFO order: LOADB_reg(k+1) issued BEFORE gather ISSUE(k+1), so
//     no consumption ever drains the in-flight gathers. Barriers (2/k,
//     lgkm-only) gate only the B buffer.
//   prep : weight casts (w1b, w2b, wdb, wofb all bf16)
//   k1   : x -> 1x1 conv (512->128)+bn1+relu, MFMA -> out1b (NHWC bf16, d_out)
//   k3   : offset conv (fused) + deformable 3x3 (128->128)+bn2 -> out2b
//   k4   : 1x1 conv (128->512)+bn3+residual+relu, MFMA -> d_out (CHW f32)
// out1b lives in d_out's first 25.7 MB (d_out fully rewritten by k4).
// ---------------------------------------------------------------------------

typedef __attribute__((ext_vector_type(8))) short short8;  // 8 bf16 = 4 VGPR
typedef __attribute__((ext_vector_type(4))) float f32x4;

constexpr int Bn = 8;
constexpr int IC = 512;
constexpr int Cc = 128;
constexpr int Hh = 112;
constexpr int Ww = 112;
constexpr int Pp = Hh * Ww;          // 12544
constexpr float EPSf = 1e-5f;

// workspace layout (float units)
constexpr size_t OFS_OUT2B = 2097152;                           // ushort[8*12544*128] (25.7 MB)
constexpr size_t OFS_W1B   = (size_t)Bn * Pp * IC / 2;          // ushort[128*512]
constexpr size_t OFS_W2B   = OFS_W1B + (size_t)Cc * IC / 2;     // ushort[512*128]
constexpr size_t OFS_WDB   = OFS_W2B + (size_t)IC * Cc / 2;     // ushort[9*128*128] (k,oc,ic)
constexpr size_t OFS_WOFB  = OFS_WDB + (size_t)9 * Cc * Cc / 2; // ushort[9*32*128]  (k,oc,ic)

__device__ __forceinline__ ushort f2bf(float f) {   // round-to-nearest-even
  uint u = __float_as_uint(f);
  return (ushort)((u + 0x7fffu + ((u >> 16) & 1u)) >> 16);
}
__device__ __forceinline__ float bfLO(uint u) {     // f32 of low bf16
  return __uint_as_float(u << 16);
}
__device__ __forceinline__ float bfHI(uint u) {     // f32 of high bf16
  return __uint_as_float(u & 0xffff0000u);
}
__device__ __forceinline__ uint cvtpk(float a, float b) {  // (a:lo, b:hi) bf16 pair
  __hip_bfloat162 h = __float22bfloat162_rn(make_float2(a, b));
  return *(uint*)&h;
}

// ---------------------------------------------------------------------------
__global__ __launch_bounds__(256) void prep_kernel(
    const float* __restrict__ w1, const float* __restrict__ w2,
    const float* __restrict__ wd, const float* __restrict__ woff,
    float* __restrict__ ws) {
  ushort* w1b  = (ushort*)(ws + OFS_W1B);
  ushort* w2b  = (ushort*)(ws + OFS_W2B);
  ushort* wdb  = (ushort*)(ws + OFS_WDB);
  ushort* wofb = (ushort*)(ws + OFS_WOFB);
  const int n1 = Cc * IC;          // w1b  (w1 already [oc][ic])
  const int n2 = IC * Cc;          // w2b  (w2 already [oc][ic])
  const int n3 = 9 * Cc * Cc;      // wdb  [k][oc][ic]
  const int n4 = 9 * 32 * Cc;      // wofb [k][oc(pad32)][ic]
  const int total = n1 + n2 + n3 + n4;
  for (int idx = blockIdx.x * blockDim.x + threadIdx.x; idx < total;
       idx += gridDim.x * blockDim.x) {
    if (idx < n1) {
      w1b[idx] = f2bf(w1[idx]);
    } else if (idx < n1 + n2) {
      int t = idx - n1;
      w2b[t] = f2bf(w2[t]);
    } else if (idx < n1 + n2 + n3) {
      int t = idx - n1 - n2;
      int k = t / (Cc * Cc), r = t % (Cc * Cc);
      int oc = r / Cc, ic = r % Cc;
      wdb[t] = f2bf(wd[(oc * Cc + ic) * 9 + k]);
    } else {
      int t = idx - n1 - n2 - n3;
      int k = t / (32 * Cc), r = t % (32 * Cc);
      int oc = r / Cc, ic = r % Cc;
      wofb[t] = (oc < 18) ? f2bf(woff[(oc * Cc + ic) * 9 + k]) : (ushort)0;
    }
  }
}

// ---------------------------------------------------------------------------
// k1 (round 13): 1x1 conv (512->128) + bn1 + relu via MFMA.
// Block: 128 px x 128 oc. 16 ic-chunks of 32.
__global__ __launch_bounds__(256) void k1_fused_mfma(
    const float* __restrict__ x, const ushort* __restrict__ w1b,
    const float* __restrict__ b1, const float* __restrict__ g1,
    const float* __restrict__ be1, const float* __restrict__ m1,
    const float* __restrict__ v1, ushort* __restrict__ out1b) {
  __shared__ ushort smem[26624];   // At 2*8192 + Wl 2*5120 = 53248 B

  const int tid = threadIdx.x;
  const int lane = tid & 63;
  const int wv = tid >> 6;
  const int lr = lane & 15, lg = lane >> 4;
  const int orig = blockIdx.x;
  const int bid = (orig & 7) * 98 + (orig >> 3);   // bijective: 784 = 8*98
  const int bi = bid / 98;
  const int pblk = (bid % 98) * 128;

  float xs[2][4][2][2];   // [slot][q(row-pair)][parity][e(px half)]
  short8 wsv[2][2];       // [slot][instr]

#define BAR_LGKM asm volatile("s_waitcnt lgkmcnt(0)\ns_barrier" ::: "memory")

#define LOADX(c, s)                                                       \
  {                                                                       \
    const float* xb_ = x + ((size_t)bi * IC + (size_t)((c) * 32 + wv * 8)) * Pp \
                         + pblk + lane;                                   \
    _Pragma("unroll") for (int q = 0; q < 4; ++q) {                       \
      _Pragma("unroll") for (int p = 0; p < 2; ++p) {                     \
        xs[s][q][p][0] = xb_[(size_t)(2 * q + p) * Pp];                   \
        xs[s][q][p][1] = xb_[(size_t)(2 * q + p) * Pp + 64];              \
      }                                                                   \
    }                                                                     \
  }

#define LOADW(c, s)                                                       \
  {                                                                       \
    const ushort* wb_ = w1b + (size_t)(wv * 32 + (lane >> 2)) * IC        \
                            + (c) * 32 + (lane & 3) * 8;                  \
    wsv[s][0] = *(const short8*)(wb_);                                    \
    wsv[s][1] = *(const short8*)(wb_ + (size_t)16 * IC);                  \
  }

#define WRITE(c, s)                                                       \
  {                                                                       \
    char* atb_ = (char*)smem + ((c) & 1) * 16384;                         \
    _Pragma("unroll") for (int e = 0; e < 2; ++e) {                       \
      const int px_ = lane + 64 * e;                                      \
      uint4 pk_;                                                          \
      uint* pp_ = (uint*)&pk_;                                            \
      _Pragma("unroll") for (int q = 0; q < 4; ++q)                       \
        pp_[q] = cvtpk(xs[s][q][0][e], xs[s][q][1][e]);                   \
      *(uint4*)(atb_ + px_ * 128 + ((wv ^ (px_ & 7)) << 4)) = pk_;        \
    }                                                                     \
    ushort* wlb_ = smem + 16384 + ((c) & 1) * 5120;                       \
    *(short8*)(wlb_ + (wv * 32 + (lane >> 2)) * 40 + (lane & 3) * 8) = wsv[s][0]; \
    *(short8*)(wlb_ + (wv * 32 + 16 + (lane >> 2)) * 40 + (lane & 3) * 8) = wsv[s][1]; \
  }

  f32x4 acc[2][8];
#pragma unroll
  for (int m = 0; m < 2; ++m)
#pragma unroll
    for (int n = 0; n < 8; ++n) acc[m][n] = (f32x4)0.f;

  LOADX(0, 0) LOADW(0, 0)
  LOADX(1, 1) LOADW(1, 1)

#pragma unroll
  for (int c = 0; c < 16; ++c) {
    WRITE(c, c & 1);
    BAR_LGKM;
    if (c + 2 < 16) { LOADX(c + 2, c & 1) LOADW(c + 2, c & 1) }

    {
      const char* atb = (const char*)smem + (c & 1) * 16384;
      const ushort* wlb = smem + 16384 + (c & 1) * 5120;
      const int sw = (lg ^ (lr & 7)) << 4;
      short8 a0 = *(const short8*)(atb + (wv * 32 + lr) * 128 + sw);
      short8 a1 = *(const short8*)(atb + (wv * 32 + 16 + lr) * 128 + sw);
#pragma unroll
      for (int n = 0; n < 8; ++n) {
        short8 b = *(const short8*)(wlb + (n * 16 + lr) * 40 + lg * 8);
        acc[0][n] = __builtin_amdgcn_mfma_f32_16x16x32_bf16(a0, b, acc[0][n], 0, 0, 0);
        acc[1][n] = __builtin_amdgcn_mfma_f32_16x16x32_bf16(a1, b, acc[1][n], 0, 0, 0);
      }
    }
  }

#undef LOADX
#undef LOADW
#undef WRITE
#undef BAR_LGKM

  __syncthreads();   // all MFMA reads done before Ab overlays At/Wl

  ushort(*Ab)[136] = (ushort(*)[136])smem;
#pragma unroll
  for (int n = 0; n < 8; ++n) {
    int oc = n * 16 + lr;
    float inv = g1[oc] * rsqrtf(v1[oc] + EPSf);
    float sh = (b1[oc] - m1[oc]) * inv + be1[oc];
#pragma unroll
    for (int m = 0; m < 2; ++m) {
#pragma unroll
      for (int r = 0; r < 4; ++r) {
        int pl = wv * 32 + m * 16 + lg * 4 + r;
        Ab[pl][oc] = f2bf(fmaxf(acc[m][n][r] * inv + sh, 0.f));
      }
    }
  }
#pragma unroll
  for (int j = 0; j < 8; ++j) {
    int pl = wv * 32 + j * 4 + (lane >> 4);
    uint4 v = *(const uint4*)&Ab[pl][(lane & 15) * 8];
    *(uint4*)(out1b + ((size_t)bi * Pp + pblk + pl) * Cc + (lane & 15) * 8) = v;
  }
}

// ---------------------------------------------------------------------------
// k3 (round 21): offset conv (fused) + deformable conv + bn2.
// Deform loop: px-slice waves, gather-direct-to-fragment registers (no
// colsA / no transpose), B k-slice in LDS (reg-staged, FIFO-clean order).
__global__ __launch_bounds__(256) void k3_deform_mfma(
    const ushort* __restrict__ out1b, const ushort* __restrict__ wofb,
    const float* __restrict__ boff,
    const ushort* __restrict__ wdb, const float* __restrict__ bd,
    const float* __restrict__ g2, const float* __restrict__ be2,
    const float* __restrict__ m2, const float* __restrict__ v2,
    ushort* __restrict__ out2b) {
  __shared__ ushort Blds[128][136];     // 34.8 KB: B k-slice (pacc alias)
  __shared__ float meta[9 * 64 * 8];    // 18.4 KB

  const int tid = threadIdx.x;
  const int lane = tid & 63;
  const int wv = tid >> 6;
  const int lr = lane & 15, lg = lane >> 4;
  const int orig = blockIdx.x;
  const int bid = (orig & 7) * 196 + (orig >> 3);
  const int bi = bid / 196;
  const int p0 = (bid % 196) * 64;

  const ushort* src = out1b + (size_t)bi * Pp * Cc;
  float* pacc = (float*)Blds;   // pacc[w][px][33] f32 = 33.8 KB <= 34.8 KB

  // ---- Phase A: offset-conv partials for taps k = wv, wv+4, wv+8
  {
    int ohm[4], owm[4];
#pragma unroll
    for (int m = 0; m < 4; ++m) {
      int p = p0 + m * 16 + lr;
      ohm[m] = p / Ww;
      owm[m] = p - ohm[m] * Ww;
    }
    f32x4 aco[4][2];
#pragma unroll
    for (int m = 0; m < 4; ++m) { aco[m][0] = (f32x4)0.f; aco[m][1] = (f32x4)0.f; }

    for (int k = wv; k < 9; k += 4) {
      const int kdy = k / 3 - 1, kdx = k % 3 - 1;
      const ushort* rp[4];
      bool val[4];
#pragma unroll
      for (int m = 0; m < 4; ++m) {
        int yy = ohm[m] + kdy, xx = owm[m] + kdx;
        val[m] = ((unsigned)yy < (unsigned)Hh) && ((unsigned)xx < (unsigned)Ww);
        int yc = min(max(yy, 0), Hh - 1), xc = min(max(xx, 0), Ww - 1);
        rp[m] = src + (size_t)(yc * Ww + xc) * Cc;
      }
#pragma unroll
      for (int ks = 0; ks < 4; ++ks) {
        short8 b0 = *(const short8*)(wofb + (size_t)(k * 32 + lr) * Cc + ks * 32 + 8 * lg);
        short8 b1v = *(const short8*)(wofb + (size_t)(k * 32 + 16 + lr) * Cc + ks * 32 + 8 * lg);
#pragma unroll
        for (int m = 0; m < 4; ++m) {
          short8 av = *(const short8*)(rp[m] + ks * 32 + 8 * lg);
          short8 a = val[m] ? av : (short8)0;
          aco[m][0] = __builtin_amdgcn_mfma_f32_16x16x32_bf16(a, b0, aco[m][0], 0, 0, 0);
          aco[m][1] = __builtin_amdgcn_mfma_f32_16x16x32_bf16(a, b1v, aco[m][1], 0, 0, 0);
        }
      }
    }
#pragma unroll
    for (int n = 0; n < 2; ++n)
#pragma unroll
      for (int m = 0; m < 4; ++m)
#pragma unroll
        for (int r = 0; r < 4; ++r) {
          int px = m * 16 + lg * 4 + r;
          pacc[(wv * 64 + px) * 33 + n * 16 + lr] = aco[m][n][r];
        }
  }
  __syncthreads();

  // ---- Phase B: meta precompute; lane = pixel, wave wv covers its k set
  {
    const int p = p0 + lane;
    const int oh = p / Ww, ow = p - oh * Ww;
    for (int k = wv; k < 9; k += 4) {
      const int kdy = k / 3 - 1, kdx = k % 3 - 1;
      float offy = boff[2 * k], offx = boff[2 * k + 1];
#pragma unroll
      for (int w = 0; w < 4; ++w) {
        offy += pacc[(w * 64 + lane) * 33 + 2 * k];
        offx += pacc[(w * 64 + lane) * 33 + 2 * k + 1];
      }
      float py = (float)(oh + kdy) + offy;
      float pxf = (float)(ow + kdx) + offx;
      float y0f = floorf(py), x0f = floorf(pxf);
      float dy = py - y0f, dx = pxf - x0f;
      int y0 = (int)y0f, x0 = (int)x0f;
      int y1 = y0 + 1, x1 = x0 + 1;
      float wy0 = (y0 >= 0 && y0 < Hh) ? 1.f - dy : 0.f;
      float wy1 = (y1 >= 0 && y1 < Hh) ? dy : 0.f;
      float wx0 = (x0 >= 0 && x0 < Ww) ? 1.f - dx : 0.f;
      float wx1 = (x1 >= 0 && x1 < Ww) ? dx : 0.f;
      int yc0 = min(max(y0, 0), Hh - 1), yc1 = min(max(y1, 0), Hh - 1);
      int xc0 = min(max(x0, 0), Ww - 1), xc1 = min(max(x1, 0), Ww - 1);
      float* mp = &meta[(k * 64 + lane) * 8];
      mp[0] = wy0 * wx0;
      mp[1] = wy0 * wx1;
      mp[2] = wy1 * wx0;
      mp[3] = wy1 * wx1;
      int* ip = (int*)(mp + 4);
      ip[0] = (yc0 * Ww + xc0) * (Cc * 2);
      ip[1] = (yc0 * Ww + xc1) * (Cc * 2);
      ip[2] = (yc1 * Ww + xc0) * (Cc * 2);
      ip[3] = (yc1 * Ww + xc1) * (Cc * 2);
    }
  }
  __syncthreads();   // meta visible; pacc reads done (Blds free for B)

  // ---- deform main loop: px-slice, gather-direct-to-fragment
  f32x4 acc[8];
#pragma unroll
  for (int n = 0; n < 8; ++n) acc[n] = (f32x4)0.f;

  // this lane gathers for px = p0 + wv*16 + lr, channel bytes lg*16 + ks*64
  const char* sbase = (const char*)src + lg * 16;

  uint4 gv[4][4];    // [ks][corner] in-flight gather data for k(+1)
  float4 gwv;        // bilinear weights of the in-flight k
  short8 Areg[4];    // combined A-fragments for current k
  short8 Breg[8];    // B staging registers (this wave's 8KB portion)

  // B staging role: lane covers row wv*32 + (lane>>1), half (lane&1)*128B
  const int brow = wv * 32 + (lane >> 1);
  const int bcol8 = (lane & 1) * 64;    // ushort offset of 128B half

#define BAR_LGKM asm volatile("s_waitcnt lgkmcnt(0)\ns_barrier" ::: "memory")

#define LOADB_REG(kk)                                                    \
  {                                                                      \
    const ushort* q_ = wdb + (size_t)(kk) * Cc * Cc + (size_t)brow * Cc + bcol8; \
    _Pragma("unroll") for (int i = 0; i < 8; ++i)                        \
      Breg[i] = *(const short8*)(q_ + i * 8);                            \
  }

#define DSWRITE_B                                                        \
  {                                                                      \
    ushort* d_ = &Blds[brow][bcol8];                                     \
    _Pragma("unroll") for (int i = 0; i < 8; ++i)                        \
      *(short8*)(d_ + i * 8) = Breg[i];                                  \
  }

#define ISSUEG(kk)                                                       \
  {                                                                      \
    const float* mp_ = &meta[((kk) * 64 + wv * 16 + lr) * 8];            \
    gwv = *(const float4*)mp_;                                           \
    int4 go_ = *(const int4*)(mp_ + 4);                                  \
    _Pragma("unroll") for (int ks = 0; ks < 4; ++ks) {                   \
      gv[ks][0] = *(const uint4*)(sbase + go_.x + ks * 64);              \
      gv[ks][1] = *(const uint4*)(sbase + go_.y + ks * 64);              \
      gv[ks][2] = *(const uint4*)(sbase + go_.z + ks * 64);              \
      gv[ks][3] = *(const uint4*)(sbase + go_.w + ks * 64);              \
    }                                                                    \
  }

#define COMBINE                                                          \
  {                                                                      \
    _Pragma("unroll") for (int ks = 0; ks < 4; ++ks) {                   \
      uint4 pk_;                                                         \
      uint* pp_ = (uint*)&pk_;                                           \
      _Pragma("unroll") for (int j = 0; j < 4; ++j) {                    \
        uint a0_ = ((const uint*)&gv[ks][0])[j];                         \
        uint a1_ = ((const uint*)&gv[ks][1])[j];                         \
        uint a2_ = ((const uint*)&gv[ks][2])[j];                         \
        uint a3_ = ((const uint*)&gv[ks][3])[j];                         \
        float lo_ = gwv.x * bfLO(a0_) + gwv.y * bfLO(a1_)                \
                  + gwv.z * bfLO(a2_) + gwv.w * bfLO(a3_);               \
        float hi_ = gwv.x * bfHI(a0_) + gwv.y * bfHI(a1_)                \
                  + gwv.z * bfHI(a2_) + gwv.w * bfHI(a3_);               \
        pp_[j] = cvtpk(lo_, hi_);                                        \
      }                                                                  \
      Areg[ks] = *(short8*)&pk_;                                         \
    }                                                                    \
  }

  // ---- prologue: B(0) regs (oldest), gathers G(0), B(0)->LDS, barrier
  LOADB_REG(0)
  ISSUEG(0)
  DSWRITE_B          // waits Breg(0) only; G(0) newer, stays in flight
  BAR_LGKM;          // B(0) visible

  for (int k = 0; k < 9; ++k) {
    COMBINE                                   // G(k) -> Areg (drains <= G(k))
    if (k < 8) {
      LOADB_REG(k + 1)                        // issued BEFORE G(k+1)
      ISSUEG(k + 1)                           // gathers in flight across MFMA
    }

    // ---- MFMA: Areg x Blds (no vmem waits -> gathers survive)
#pragma unroll
    for (int ks = 0; ks < 4; ++ks) {
#pragma unroll
      for (int n = 0; n < 8; ++n) {
        short8 b = *(const short8*)&Blds[n * 16 + lr][ks * 32 + 8 * lg];
        acc[n] = __builtin_amdgcn_mfma_f32_16x16x32_bf16(Areg[ks], b, acc[n], 0, 0, 0);
      }
    }

    if (k < 8) {
      BAR_LGKM;      // all waves' B(k) ds_reads complete
      DSWRITE_B      // waits Breg(k+1) (older than G(k+1)) -> gathers survive
      BAR_LGKM;      // B(k+1) visible
    }
  }

#undef LOADB_REG
#undef DSWRITE_B
#undef ISSUEG
#undef COMBINE
#undef BAR_LGKM

  // ---- epilogue: bn2, write this wave's 16 px x 128 oc
#pragma unroll
  for (int n = 0; n < 8; ++n) {
    int oc = n * 16 + lr;
    float inv = g2[oc] * rsqrtf(v2[oc] + EPSf);
    float sh = (bd[oc] - m2[oc]) * inv + be2[oc];
#pragma unroll
    for (int r = 0; r < 4; ++r) {
      int p = p0 + wv * 16 + lg * 4 + r;
      out2b[((size_t)bi * Pp + p) * Cc + oc] = f2bf(acc[n][r] * inv + sh);
    }
  }
}

// ---------------------------------------------------------------------------
// k4 (round 18): 1x1 conv (128->512) + bn3 + residual + relu via MFMA.
// lgkm-only barriers + 1-ahead x prefetch (2-slot regs), no VGPR cap.
__global__ __launch_bounds__(256, 2) void k4_mfma(
    const ushort* __restrict__ out2b, const ushort* __restrict__ w2b,
    const float* __restrict__ b2, const float* __restrict__ g3,
    const float* __restrict__ be3, const float* __restrict__ m3,
    const float* __restrict__ v3, const float* __restrict__ x,
    float* __restrict__ out) {
  __shared__ float obuf[2][16][260];   // 33.3 KB, double-buffered per n-frag

  const int tid = threadIdx.x;
  const int lane = tid & 63;
  const int wv = tid >> 6;
  const int lr = lane & 15, lg = lane >> 4;
  const int orig = blockIdx.x;
  const int bid = (orig & 7) * 392 + (orig >> 3);   // bijective: 3136 = 8*392
  const int bi = bid / 392;
  const int r392 = bid % 392;
  const int oc_t = r392 / 49;                        // 0..7: 64-oc tile
  const int pblk = (r392 % 49) * 256;                // block px base
  const int p0 = pblk + wv * 64;                     // wave's 64-px slice (MFMA)
  const int ocb = oc_t * 64;

  const ushort* A = out2b + ((size_t)bi * Pp + p0) * Cc;
  const ushort* Bw = w2b + (size_t)ocb * Cc;

  f32x4 acc[4][4];
#pragma unroll
  for (int m = 0; m < 4; ++m)
#pragma unroll
    for (int n = 0; n < 4; ++n) acc[m][n] = (f32x4)0.f;

#pragma unroll
  for (int ks = 0; ks < 4; ++ks) {
    short8 a[4];
#pragma unroll
    for (int m = 0; m < 4; ++m)
      a[m] = *(const short8*)(A + (size_t)(m * 16 + lr) * Cc + ks * 32 + 8 * lg);
#pragma unroll
    for (int n = 0; n < 4; ++n) {
      short8 b = *(const short8*)(Bw + (size_t)(n * 16 + lr) * Cc + ks * 32 + 8 * lg);
#pragma unroll
      for (int m = 0; m < 4; ++m)
        acc[m][n] = __builtin_amdgcn_mfma_f32_16x16x32_bf16(a[m], b, acc[m][n], 0, 0, 0);
    }
  }

  // ---- epilogue: pipelined relayout. Per fragment:
  //   dump(n) -> issue x(n+1) -> lgkm-bar -> read(n)+add+store.
  float4 xv[2][4];  // [slot][it] residual x, slot = n&1

#define BARL asm volatile("s_waitcnt lgkmcnt(0)\ns_barrier" ::: "memory")
#define LOADXV(n, s)                                                      \
  {                                                                       \
    _Pragma("unroll") for (int it = 0; it < 4; ++it) {                    \
      int oc_ = ocb + (n) * 16 + it * 4 + wv;                             \
      xv[s][it] = *(const float4*)(x + ((size_t)bi * IC + oc_) * Pp       \
                                   + pblk + lane * 4);                    \
    }                                                                     \
  }

  LOADXV(0, 0)

#pragma unroll
  for (int n = 0; n < 4; ++n) {
    {
      int ocw = ocb + n * 16 + lr;   // writer lane's oc (fragment column)
      float inv = g3[ocw] * rsqrtf(v3[ocw] + EPSf);
      float sh = (b2[ocw] - m3[ocw]) * inv + be3[ocw];
      float(*buf)[260] = obuf[n & 1];
#pragma unroll
      for (int m = 0; m < 4; ++m) {
        float4 o;
        o.x = acc[m][n][0] * inv + sh;
        o.y = acc[m][n][1] * inv + sh;
        o.z = acc[m][n][2] * inv + sh;
        o.w = acc[m][n][3] * inv + sh;
        *(float4*)&buf[lr][wv * 64 + m * 16 + lg * 4] = o;
      }
    }
    if (n < 3) { LOADXV(n + 1, (n + 1) & 1) }   // in flight across BARL
    BARL;
    {
      const float(*buf)[260] = obuf[n & 1];
#pragma unroll
      for (int it = 0; it < 4; ++it) {
        int r = it * 4 + wv;                 // oc row within fragment
        int oc = ocb + n * 16 + r;
        float4 v = *(const float4*)&buf[r][lane * 4];
        float4 xr = xv[n & 1][it];
        float4 o;
        o.x = fmaxf(v.x + xr.x, 0.f);
        o.y = fmaxf(v.y + xr.y, 0.f);
        o.z = fmaxf(v.z + xr.z, 0.f);
        o.w = fmaxf(v.w + xr.w, 0.f);
        *(float4*)(out + ((size_t)bi * IC + oc) * Pp + pblk + lane * 4) = o;
      }
    }
  }
#undef BARL
#undef LOADXV
}

// ---------------------------------------------------------------------------
extern "C" void kernel_launch(void* const* d_in, const int* in_sizes, int n_in,
                              void* d_out, int out_size, void* d_ws, size_t ws_size,
                              hipStream_t stream) {
  const float* x    = (const float*)d_in[0];
  const float* w1   = (const float*)d_in[1];
  const float* b1   = (const float*)d_in[2];
  const float* g1   = (const float*)d_in[3];
  const float* be1  = (const float*)d_in[4];
  const float* m1   = (const float*)d_in[5];
  const float* v1   = (const float*)d_in[6];
  const float* woff = (const float*)d_in[7];
  const float* boff = (const float*)d_in[8];
  const float* wd   = (const float*)d_in[9];
  const float* bd   = (const float*)d_in[10];
  const float* g2   = (const float*)d_in[11];
  const float* be2  = (const float*)d_in[12];
  const float* m2   = (const float*)d_in[13];
  const float* v2   = (const float*)d_in[14];
  const float* w2   = (const float*)d_in[15];
  const float* b2   = (const float*)d_in[16];
  const float* g3   = (const float*)d_in[17];
  const float* be3  = (const float*)d_in[18];
  const float* m3   = (const float*)d_in[19];
  const float* v3   = (const float*)d_in[20];

  float* ws   = (float*)d_ws;
  float* out  = (float*)d_out;
  ushort* out2b = (ushort*)(ws + OFS_OUT2B);
  ushort* w1b   = (ushort*)(ws + OFS_W1B);
  ushort* w2b   = (ushort*)(ws + OFS_W2B);
  ushort* wdb   = (ushort*)(ws + OFS_WDB);
  ushort* wofb  = (ushort*)(ws + OFS_WOFB);
  ushort* out1b = (ushort*)d_out;                // scratch in d_out (k4 rewrites all)

  prep_kernel<<<512, 256, 0, stream>>>(w1, w2, wd, woff, ws);
  k1_fused_mfma<<<Bn * 98, 256, 0, stream>>>(x, w1b, b1, g1, be1, m1, v1, out1b);
  k3_deform_mfma<<<Bn * 196, 256, 0, stream>>>(out1b, wofb, boff, wdb, bd,
                                               g2, be2, m2, v2, out2b);
  k4_mfma<<<Bn * 392, 256, 0, stream>>>(out2b, w2b, b2, g3, be3, m3, v3, x, out);
}

// Round 15
// 310.478 us; speedup vs baseline: 1.2227x; 1.2227x over previous
//
#include <hip/hip_runtime.h>
#include <hip/hip_bf16.h>

// ---------------------------------------------------------------------------
// Deformable bottleneck. Round 22 = R18 revert (best measured: 311.15 us).
// R21's px-slice/B-in-LDS rewrite failed its pre-committed criterion
// (k3 228 us; SQ_LDS_BANK_CONFLICT 4.2M -> 11.9M from 272-B row-stride
// B-reads at 4x LDS volume). Session-verified wins retained:
//   - k1: 256-B contiguous x reads, dbuf LDS, 1KB contiguous stores (R13)
//   - k2 fused into k3's prologue (R15)
//   - k3: lgkm-only barriers, 4-chunk in-flight gather pipeline (R10)
//   - k4: LDS epilogue relayout -> 1-KB contiguous x-reads/stores (R9),
//         lgkm-only barriers + 1-ahead x prefetch (R18)
//   prep : weight casts (w1b, w2b, wdb, wofb all bf16)
//   k1   : x -> 1x1 conv (512->128)+bn1+relu, MFMA -> out1b (NHWC bf16, d_out)
//   k3   : offset conv (fused) + deformable 3x3 (128->128)+bn2 -> out2b
//   k4   : 1x1 conv (128->512)+bn3+residual+relu, MFMA -> d_out (CHW f32)
// out1b lives in d_out's first 25.7 MB (d_out fully rewritten by k4).
// ---------------------------------------------------------------------------

typedef __attribute__((ext_vector_type(8))) short short8;  // 8 bf16 = 4 VGPR
typedef __attribute__((ext_vector_type(4))) float f32x4;

constexpr int Bn = 8;
constexpr int IC = 512;
constexpr int Cc = 128;
constexpr int Hh = 112;
constexpr int Ww = 112;
constexpr int Pp = Hh * Ww;          // 12544
constexpr float EPSf = 1e-5f;

// workspace layout (float units)
constexpr size_t OFS_OUT2B = 2097152;                           // ushort[8*12544*128] (25.7 MB)
constexpr size_t OFS_W1B   = (size_t)Bn * Pp * IC / 2;          // ushort[128*512]
constexpr size_t OFS_W2B   = OFS_W1B + (size_t)Cc * IC / 2;     // ushort[512*128]
constexpr size_t OFS_WDB   = OFS_W2B + (size_t)IC * Cc / 2;     // ushort[9*128*128] (k,oc,ic)
constexpr size_t OFS_WOFB  = OFS_WDB + (size_t)9 * Cc * Cc / 2; // ushort[9*32*128]  (k,oc,ic)

__device__ __forceinline__ ushort f2bf(float f) {   // round-to-nearest-even
  uint u = __float_as_uint(f);
  return (ushort)((u + 0x7fffu + ((u >> 16) & 1u)) >> 16);
}
__device__ __forceinline__ float bfLO(uint u) {     // f32 of low bf16
  return __uint_as_float(u << 16);
}
__device__ __forceinline__ float bfHI(uint u) {     // f32 of high bf16
  return __uint_as_float(u & 0xffff0000u);
}
__device__ __forceinline__ uint cvtpk(float a, float b) {  // (a:lo, b:hi) bf16 pair
  __hip_bfloat162 h = __float22bfloat162_rn(make_float2(a, b));
  return *(uint*)&h;
}

// ---------------------------------------------------------------------------
__global__ __launch_bounds__(256) void prep_kernel(
    const float* __restrict__ w1, const float* __restrict__ w2,
    const float* __restrict__ wd, const float* __restrict__ woff,
    float* __restrict__ ws) {
  ushort* w1b  = (ushort*)(ws + OFS_W1B);
  ushort* w2b  = (ushort*)(ws + OFS_W2B);
  ushort* wdb  = (ushort*)(ws + OFS_WDB);
  ushort* wofb = (ushort*)(ws + OFS_WOFB);
  const int n1 = Cc * IC;          // w1b  (w1 already [oc][ic])
  const int n2 = IC * Cc;          // w2b  (w2 already [oc][ic])
  const int n3 = 9 * Cc * Cc;      // wdb  [k][oc][ic]
  const int n4 = 9 * 32 * Cc;      // wofb [k][oc(pad32)][ic]
  const int total = n1 + n2 + n3 + n4;
  for (int idx = blockIdx.x * blockDim.x + threadIdx.x; idx < total;
       idx += gridDim.x * blockDim.x) {
    if (idx < n1) {
      w1b[idx] = f2bf(w1[idx]);
    } else if (idx < n1 + n2) {
      int t = idx - n1;
      w2b[t] = f2bf(w2[t]);
    } else if (idx < n1 + n2 + n3) {
      int t = idx - n1 - n2;
      int k = t / (Cc * Cc), r = t % (Cc * Cc);
      int oc = r / Cc, ic = r % Cc;
      wdb[t] = f2bf(wd[(oc * Cc + ic) * 9 + k]);
    } else {
      int t = idx - n1 - n2 - n3;
      int k = t / (32 * Cc), r = t % (32 * Cc);
      int oc = r / Cc, ic = r % Cc;
      wofb[t] = (oc < 18) ? f2bf(woff[(oc * Cc + ic) * 9 + k]) : (ushort)0;
    }
  }
}

// ---------------------------------------------------------------------------
// k1 (round 13): 1x1 conv (512->128) + bn1 + relu via MFMA.
// Block: 128 px x 128 oc. 16 ic-chunks of 32.
__global__ __launch_bounds__(256) void k1_fused_mfma(
    const float* __restrict__ x, const ushort* __restrict__ w1b,
    const float* __restrict__ b1, const float* __restrict__ g1,
    const float* __restrict__ be1, const float* __restrict__ m1,
    const float* __restrict__ v1, ushort* __restrict__ out1b) {
  __shared__ ushort smem[26624];   // At 2*8192 + Wl 2*5120 = 53248 B

  const int tid = threadIdx.x;
  const int lane = tid & 63;
  const int wv = tid >> 6;
  const int lr = lane & 15, lg = lane >> 4;
  const int orig = blockIdx.x;
  const int bid = (orig & 7) * 98 + (orig >> 3);   // bijective: 784 = 8*98
  const int bi = bid / 98;
  const int pblk = (bid % 98) * 128;

  float xs[2][4][2][2];   // [slot][q(row-pair)][parity][e(px half)]
  short8 wsv[2][2];       // [slot][instr]

#define BAR_LGKM asm volatile("s_waitcnt lgkmcnt(0)\ns_barrier" ::: "memory")

#define LOADX(c, s)                                                       \
  {                                                                       \
    const float* xb_ = x + ((size_t)bi * IC + (size_t)((c) * 32 + wv * 8)) * Pp \
                         + pblk + lane;                                   \
    _Pragma("unroll") for (int q = 0; q < 4; ++q) {                       \
      _Pragma("unroll") for (int p = 0; p < 2; ++p) {                     \
        xs[s][q][p][0] = xb_[(size_t)(2 * q + p) * Pp];                   \
        xs[s][q][p][1] = xb_[(size_t)(2 * q + p) * Pp + 64];              \
      }                                                                   \
    }                                                                     \
  }

#define LOADW(c, s)                                                       \
  {                                                                       \
    const ushort* wb_ = w1b + (size_t)(wv * 32 + (lane >> 2)) * IC        \
                            + (c) * 32 + (lane & 3) * 8;                  \
    wsv[s][0] = *(const short8*)(wb_);                                    \
    wsv[s][1] = *(const short8*)(wb_ + (size_t)16 * IC);                  \
  }

#define WRITE(c, s)                                                       \
  {                                                                       \
    char* atb_ = (char*)smem + ((c) & 1) * 16384;                         \
    _Pragma("unroll") for (int e = 0; e < 2; ++e) {                       \
      const int px_ = lane + 64 * e;                                      \
      uint4 pk_;                                                          \
      uint* pp_ = (uint*)&pk_;                                            \
      _Pragma("unroll") for (int q = 0; q < 4; ++q)                       \
        pp_[q] = cvtpk(xs[s][q][0][e], xs[s][q][1][e]);                   \
      *(uint4*)(atb_ + px_ * 128 + ((wv ^ (px_ & 7)) << 4)) = pk_;        \
    }                                                                     \
    ushort* wlb_ = smem + 16384 + ((c) & 1) * 5120;                       \
    *(short8*)(wlb_ + (wv * 32 + (lane >> 2)) * 40 + (lane & 3) * 8) = wsv[s][0]; \
    *(short8*)(wlb_ + (wv * 32 + 16 + (lane >> 2)) * 40 + (lane & 3) * 8) = wsv[s][1]; \
  }

  f32x4 acc[2][8];
#pragma unroll
  for (int m = 0; m < 2; ++m)
#pragma unroll
    for (int n = 0; n < 8; ++n) acc[m][n] = (f32x4)0.f;

  LOADX(0, 0) LOADW(0, 0)
  LOADX(1, 1) LOADW(1, 1)

#pragma unroll
  for (int c = 0; c < 16; ++c) {
    WRITE(c, c & 1);
    BAR_LGKM;
    if (c + 2 < 16) { LOADX(c + 2, c & 1) LOADW(c + 2, c & 1) }

    {
      const char* atb = (const char*)smem + (c & 1) * 16384;
      const ushort* wlb = smem + 16384 + (c & 1) * 5120;
      const int sw = (lg ^ (lr & 7)) << 4;
      short8 a0 = *(const short8*)(atb + (wv * 32 + lr) * 128 + sw);
      short8 a1 = *(const short8*)(atb + (wv * 32 + 16 + lr) * 128 + sw);
#pragma unroll
      for (int n = 0; n < 8; ++n) {
        short8 b = *(const short8*)(wlb + (n * 16 + lr) * 40 + lg * 8);
        acc[0][n] = __builtin_amdgcn_mfma_f32_16x16x32_bf16(a0, b, acc[0][n], 0, 0, 0);
        acc[1][n] = __builtin_amdgcn_mfma_f32_16x16x32_bf16(a1, b, acc[1][n], 0, 0, 0);
      }
    }
  }

#undef LOADX
#undef LOADW
#undef WRITE
#undef BAR_LGKM

  __syncthreads();   // all MFMA reads done before Ab overlays At/Wl

  ushort(*Ab)[136] = (ushort(*)[136])smem;
#pragma unroll
  for (int n = 0; n < 8; ++n) {
    int oc = n * 16 + lr;
    float inv = g1[oc] * rsqrtf(v1[oc] + EPSf);
    float sh = (b1[oc] - m1[oc]) * inv + be1[oc];
#pragma unroll
    for (int m = 0; m < 2; ++m) {
#pragma unroll
      for (int r = 0; r < 4; ++r) {
        int pl = wv * 32 + m * 16 + lg * 4 + r;
        Ab[pl][oc] = f2bf(fmaxf(acc[m][n][r] * inv + sh, 0.f));
      }
    }
  }
#pragma unroll
  for (int j = 0; j < 8; ++j) {
    int pl = wv * 32 + j * 4 + (lane >> 4);
    uint4 v = *(const uint4*)&Ab[pl][(lane & 15) * 8];
    *(uint4*)(out1b + ((size_t)bi * Pp + pblk + pl) * Cc + (lane & 15) * 8) = v;
  }
}

// ---------------------------------------------------------------------------
// k3 (round 15): offset conv (fused) + deformable conv + bn2.
__global__ __launch_bounds__(256) void k3_deform_mfma(
    const ushort* __restrict__ out1b, const ushort* __restrict__ wofb,
    const float* __restrict__ boff,
    const ushort* __restrict__ wdb, const float* __restrict__ bd,
    const float* __restrict__ g2, const float* __restrict__ be2,
    const float* __restrict__ m2, const float* __restrict__ v2,
    ushort* __restrict__ out2b) {
  __shared__ ushort colsA[2][64][136];  // 34.8 KB double buffer (pacc alias)
  __shared__ float meta[9 * 64 * 8];    // 18.4 KB

  const int tid = threadIdx.x;
  const int lane = tid & 63;
  const int wv = tid >> 6;
  const int lr = lane & 15, lg = lane >> 4;
  const int orig = blockIdx.x;
  const int bid = (orig & 7) * 196 + (orig >> 3);
  const int bi = bid / 196;
  const int p0 = (bid % 196) * 64;

  const ushort* src = out1b + (size_t)bi * Pp * Cc;
  float* pacc = (float*)colsA;   // pacc[w][px][33] f32 = 33.8 KB <= 34.8 KB

  // ---- Phase A: offset-conv partials for taps k = wv, wv+4, wv+8
  {
    int ohm[4], owm[4];
#pragma unroll
    for (int m = 0; m < 4; ++m) {
      int p = p0 + m * 16 + lr;
      ohm[m] = p / Ww;
      owm[m] = p - ohm[m] * Ww;
    }
    f32x4 aco[4][2];
#pragma unroll
    for (int m = 0; m < 4; ++m) { aco[m][0] = (f32x4)0.f; aco[m][1] = (f32x4)0.f; }

    for (int k = wv; k < 9; k += 4) {
      const int kdy = k / 3 - 1, kdx = k % 3 - 1;
      const ushort* rp[4];
      bool val[4];
#pragma unroll
      for (int m = 0; m < 4; ++m) {
        int yy = ohm[m] + kdy, xx = owm[m] + kdx;
        val[m] = ((unsigned)yy < (unsigned)Hh) && ((unsigned)xx < (unsigned)Ww);
        int yc = min(max(yy, 0), Hh - 1), xc = min(max(xx, 0), Ww - 1);
        rp[m] = src + (size_t)(yc * Ww + xc) * Cc;
      }
#pragma unroll
      for (int ks = 0; ks < 4; ++ks) {
        short8 b0 = *(const short8*)(wofb + (size_t)(k * 32 + lr) * Cc + ks * 32 + 8 * lg);
        short8 b1v = *(const short8*)(wofb + (size_t)(k * 32 + 16 + lr) * Cc + ks * 32 + 8 * lg);
#pragma unroll
        for (int m = 0; m < 4; ++m) {
          short8 av = *(const short8*)(rp[m] + ks * 32 + 8 * lg);
          short8 a = val[m] ? av : (short8)0;
          aco[m][0] = __builtin_amdgcn_mfma_f32_16x16x32_bf16(a, b0, aco[m][0], 0, 0, 0);
          aco[m][1] = __builtin_amdgcn_mfma_f32_16x16x32_bf16(a, b1v, aco[m][1], 0, 0, 0);
        }
      }
    }
#pragma unroll
    for (int n = 0; n < 2; ++n)
#pragma unroll
      for (int m = 0; m < 4; ++m)
#pragma unroll
        for (int r = 0; r < 4; ++r) {
          int px = m * 16 + lg * 4 + r;
          pacc[(wv * 64 + px) * 33 + n * 16 + lr] = aco[m][n][r];
        }
  }
  __syncthreads();

  // ---- Phase B: meta precompute; lane = pixel, wave wv covers its k set
  {
    const int p = p0 + lane;
    const int oh = p / Ww, ow = p - oh * Ww;
    for (int k = wv; k < 9; k += 4) {
      const int kdy = k / 3 - 1, kdx = k % 3 - 1;
      float offy = boff[2 * k], offx = boff[2 * k + 1];
#pragma unroll
      for (int w = 0; w < 4; ++w) {
        offy += pacc[(w * 64 + lane) * 33 + 2 * k];
        offx += pacc[(w * 64 + lane) * 33 + 2 * k + 1];
      }
      float py = (float)(oh + kdy) + offy;
      float pxf = (float)(ow + kdx) + offx;
      float y0f = floorf(py), x0f = floorf(pxf);
      float dy = py - y0f, dx = pxf - x0f;
      int y0 = (int)y0f, x0 = (int)x0f;
      int y1 = y0 + 1, x1 = x0 + 1;
      float wy0 = (y0 >= 0 && y0 < Hh) ? 1.f - dy : 0.f;
      float wy1 = (y1 >= 0 && y1 < Hh) ? dy : 0.f;
      float wx0 = (x0 >= 0 && x0 < Ww) ? 1.f - dx : 0.f;
      float wx1 = (x1 >= 0 && x1 < Ww) ? dx : 0.f;
      int yc0 = min(max(y0, 0), Hh - 1), yc1 = min(max(y1, 0), Hh - 1);
      int xc0 = min(max(x0, 0), Ww - 1), xc1 = min(max(x1, 0), Ww - 1);
      float* mp = &meta[(k * 64 + lane) * 8];
      mp[0] = wy0 * wx0;
      mp[1] = wy0 * wx1;
      mp[2] = wy1 * wx0;
      mp[3] = wy1 * wx1;
      int* ip = (int*)(mp + 4);
      ip[0] = (yc0 * Ww + xc0) * (Cc * 2);
      ip[1] = (yc0 * Ww + xc1) * (Cc * 2);
      ip[2] = (yc1 * Ww + xc0) * (Cc * 2);
      ip[3] = (yc1 * Ww + xc1) * (Cc * 2);
    }
  }
  __syncthreads();

  f32x4 acc[4][2];
#pragma unroll
  for (int m = 0; m < 4; ++m) { acc[m][0] = (f32x4)0.f; acc[m][1] = (f32x4)0.f; }

  const int pxq = lane >> 4;       // which px of the quad (0..3)
  const int l16 = lane & 15;       // 8-ch block id
  const char* sb = (const char*)src + l16 * 16;

  uint4 gv[4][4];   // [t-iter][corner] in-flight corner data
  float4 gw[4];     // [t-iter] bilinear weights

#define BAR_LGKM asm volatile("s_waitcnt lgkmcnt(0)\ns_barrier" ::: "memory")

#define ISSUE(kk, t)                                                     \
  {                                                                      \
    const int px_ = wv * 16 + (t) * 4 + pxq;                             \
    const float* mp_ = &meta[((kk) * 64 + px_) * 8];                     \
    gw[t] = *(const float4*)mp_;                                         \
    int4 o4_ = *(const int4*)(mp_ + 4);                                  \
    gv[t][0] = *(const uint4*)(sb + o4_.x);                              \
    gv[t][1] = *(const uint4*)(sb + o4_.y);                              \
    gv[t][2] = *(const uint4*)(sb + o4_.z);                              \
    gv[t][3] = *(const uint4*)(sb + o4_.w);                              \
  }

#define COMMIT(buf, t)                                                   \
  {                                                                      \
    const int px_ = wv * 16 + (t) * 4 + pxq;                             \
    float4 w4_ = gw[t];                                                  \
    uint4 pk_;                                                           \
    uint* pkp_ = (uint*)&pk_;                                            \
    _Pragma("unroll")                                                    \
    for (int j = 0; j < 4; ++j) {                                        \
      uint a0_ = ((const uint*)&gv[t][0])[j];                            \
      uint a1_ = ((const uint*)&gv[t][1])[j];                            \
      uint a2_ = ((const uint*)&gv[t][2])[j];                            \
      uint a3_ = ((const uint*)&gv[t][3])[j];                            \
      float lo_ = w4_.x * bfLO(a0_) + w4_.y * bfLO(a1_)                  \
                + w4_.z * bfLO(a2_) + w4_.w * bfLO(a3_);                 \
      float hi_ = w4_.x * bfHI(a0_) + w4_.y * bfHI(a1_)                  \
                + w4_.z * bfHI(a2_) + w4_.w * bfHI(a3_);                 \
      pkp_[j] = cvtpk(lo_, hi_);                                         \
    }                                                                    \
    *(uint4*)&colsA[buf][px_][l16 * 8] = pk_;                            \
  }

  // ---- prologue: stage k=0 into buffer 0 (one serial stall), issue k=1
  ISSUE(0, 0) ISSUE(0, 1) ISSUE(0, 2) ISSUE(0, 3)
  COMMIT(0, 0) COMMIT(0, 1) COMMIT(0, 2) COMMIT(0, 3)
  ISSUE(1, 0) ISSUE(1, 1) ISSUE(1, 2) ISSUE(1, 3)
  BAR_LGKM;

  for (int k = 0; k < 9; ++k) {
    const int cur = k & 1;
    const int nxt = cur ^ 1;
    const ushort* wk = wdb + (size_t)k * Cc * Cc + (size_t)(wv * 32) * Cc;

    // ---- MFMA phase: all 16 on buffer `cur`
#pragma unroll
    for (int ks = 0; ks < 4; ++ks) {
      short8 b0 = *(const short8*)(wk + lr * Cc + ks * 32 + 8 * lg);
      short8 b1v = *(const short8*)(wk + (16 + lr) * Cc + ks * 32 + 8 * lg);
#pragma unroll
      for (int m = 0; m < 4; ++m) {
        short8 a = *(const short8*)&colsA[cur][m * 16 + lr][ks * 32 + 8 * lg];
        acc[m][0] = __builtin_amdgcn_mfma_f32_16x16x32_bf16(a, b0, acc[m][0], 0, 0, 0);
        acc[m][1] = __builtin_amdgcn_mfma_f32_16x16x32_bf16(a, b1v, acc[m][1], 0, 0, 0);
      }
    }

    // ---- commit k+1 (loads issued a full iteration ago), refill with k+2
    if (k < 8) {
      COMMIT(nxt, 0)
      if (k < 7) { ISSUE(k + 2, 0) }
      COMMIT(nxt, 1)
      if (k < 7) { ISSUE(k + 2, 1) }
      COMMIT(nxt, 2)
      if (k < 7) { ISSUE(k + 2, 2) }
      COMMIT(nxt, 3)
      if (k < 7) { ISSUE(k + 2, 3) }
      BAR_LGKM;
    }
  }

#undef ISSUE
#undef COMMIT
#undef BAR_LGKM

#pragma unroll
  for (int n = 0; n < 2; ++n) {
    int oc = wv * 32 + n * 16 + lr;
    float inv = g2[oc] * rsqrtf(v2[oc] + EPSf);
    float sh = (bd[oc] - m2[oc]) * inv + be2[oc];
#pragma unroll
    for (int m = 0; m < 4; ++m) {
#pragma unroll
      for (int r = 0; r < 4; ++r) {
        int p = p0 + m * 16 + lg * 4 + r;
        out2b[((size_t)bi * Pp + p) * Cc + oc] = f2bf(acc[m][n][r] * inv + sh);
      }
    }
  }
}

// ---------------------------------------------------------------------------
// k4 (round 18): 1x1 conv (128->512) + bn3 + residual + relu via MFMA.
// lgkm-only barriers + 1-ahead x prefetch (2-slot regs), no VGPR cap.
__global__ __launch_bounds__(256, 2) void k4_mfma(
    const ushort* __restrict__ out2b, const ushort* __restrict__ w2b,
    const float* __restrict__ b2, const float* __restrict__ g3,
    const float* __restrict__ be3, const float* __restrict__ m3,
    const float* __restrict__ v3, const float* __restrict__ x,
    float* __restrict__ out) {
  __shared__ float obuf[2][16][260];   // 33.3 KB, double-buffered per n-frag

  const int tid = threadIdx.x;
  const int lane = tid & 63;
  const int wv = tid >> 6;
  const int lr = lane & 15, lg = lane >> 4;
  const int orig = blockIdx.x;
  const int bid = (orig & 7) * 392 + (orig >> 3);   // bijective: 3136 = 8*392
  const int bi = bid / 392;
  const int r392 = bid % 392;
  const int oc_t = r392 / 49;                        // 0..7: 64-oc tile
  const int pblk = (r392 % 49) * 256;                // block px base
  const int p0 = pblk + wv * 64;                     // wave's 64-px slice (MFMA)
  const int ocb = oc_t * 64;

  const ushort* A = out2b + ((size_t)bi * Pp + p0) * Cc;
  const ushort* Bw = w2b + (size_t)ocb * Cc;

  f32x4 acc[4][4];
#pragma unroll
  for (int m = 0; m < 4; ++m)
#pragma unroll
    for (int n = 0; n < 4; ++n) acc[m][n] = (f32x4)0.f;

#pragma unroll
  for (int ks = 0; ks < 4; ++ks) {
    short8 a[4];
#pragma unroll
    for (int m = 0; m < 4; ++m)
      a[m] = *(const short8*)(A + (size_t)(m * 16 + lr) * Cc + ks * 32 + 8 * lg);
#pragma unroll
    for (int n = 0; n < 4; ++n) {
      short8 b = *(const short8*)(Bw + (size_t)(n * 16 + lr) * Cc + ks * 32 + 8 * lg);
#pragma unroll
      for (int m = 0; m < 4; ++m)
        acc[m][n] = __builtin_amdgcn_mfma_f32_16x16x32_bf16(a[m], b, acc[m][n], 0, 0, 0);
    }
  }

  // ---- epilogue: pipelined relayout. Per fragment:
  //   dump(n) -> issue x(n+1) -> lgkm-bar -> read(n)+add+store.
  float4 xv[2][4];  // [slot][it] residual x, slot = n&1

#define BARL asm volatile("s_waitcnt lgkmcnt(0)\ns_barrier" ::: "memory")
#define LOADXV(n, s)                                                      \
  {                                                                       \
    _Pragma("unroll") for (int it = 0; it < 4; ++it) {                    \
      int oc_ = ocb + (n) * 16 + it * 4 + wv;                             \
      xv[s][it] = *(const float4*)(x + ((size_t)bi * IC + oc_) * Pp       \
                                   + pblk + lane * 4);                    \
    }                                                                     \
  }

  LOADXV(0, 0)

#pragma unroll
  for (int n = 0; n < 4; ++n) {
    {
      int ocw = ocb + n * 16 + lr;   // writer lane's oc (fragment column)
      float inv = g3[ocw] * rsqrtf(v3[ocw] + EPSf);
      float sh = (b2[ocw] - m3[ocw]) * inv + be3[ocw];
      float(*buf)[260] = obuf[n & 1];
#pragma unroll
      for (int m = 0; m < 4; ++m) {
        float4 o;
        o.x = acc[m][n][0] * inv + sh;
        o.y = acc[m][n][1] * inv + sh;
        o.z = acc[m][n][2] * inv + sh;
        o.w = acc[m][n][3] * inv + sh;
        *(float4*)&buf[lr][wv * 64 + m * 16 + lg * 4] = o;
      }
    }
    if (n < 3) { LOADXV(n + 1, (n + 1) & 1) }   // in flight across BARL
    BARL;
    {
      const float(*buf)[260] = obuf[n & 1];
#pragma unroll
      for (int it = 0; it < 4; ++it) {
        int r = it * 4 + wv;                 // oc row within fragment
        int oc = ocb + n * 16 + r;
        float4 v = *(const float4*)&buf[r][lane * 4];
        float4 xr = xv[n & 1][it];
        float4 o;
        o.x = fmaxf(v.x + xr.x, 0.f);
        o.y = fmaxf(v.y + xr.y, 0.f);
        o.z = fmaxf(v.z + xr.z, 0.f);
        o.w = fmaxf(v.w + xr.w, 0.f);
        *(float4*)(out + ((size_t)bi * IC + oc) * Pp + pblk + lane * 4) = o;
      }
    }
  }
#undef BARL
#undef LOADXV
}

// ---------------------------------------------------------------------------
extern "C" void kernel_launch(void* const* d_in, const int* in_sizes, int n_in,
                              void* d_out, int out_size, void* d_ws, size_t ws_size,
                              hipStream_t stream) {
  const float* x    = (const float*)d_in[0];
  const float* w1   = (const float*)d_in[1];
  const float* b1   = (const float*)d_in[2];
  const float* g1   = (const float*)d_in[3];
  const float* be1  = (const float*)d_in[4];
  const float* m1   = (const float*)d_in[5];
  const float* v1   = (const float*)d_in[6];
  const float* woff = (const float*)d_in[7];
  const float* boff = (const float*)d_in[8];
  const float* wd   = (const float*)d_in[9];
  const float* bd   = (const float*)d_in[10];
  const float* g2   = (const float*)d_in[11];
  const float* be2  = (const float*)d_in[12];
  const float* m2   = (const float*)d_in[13];
  const float* v2   = (const float*)d_in[14];
  const float* w2   = (const float*)d_in[15];
  const float* b2   = (const float*)d_in[16];
  const float* g3   = (const float*)d_in[17];
  const float* be3  = (const float*)d_in[18];
  const float* m3   = (const float*)d_in[19];
  const float* v3   = (const float*)d_in[20];

  float* ws   = (float*)d_ws;
  float* out  = (float*)d_out;
  ushort* out2b = (ushort*)(ws + OFS_OUT2B);
  ushort* w1b   = (ushort*)(ws + OFS_W1B);
  ushort* w2b   = (ushort*)(ws + OFS_W2B);
  ushort* wdb   = (ushort*)(ws + OFS_WDB);
  ushort* wofb  = (ushort*)(ws + OFS_WOFB);
  ushort* out1b = (ushort*)d_out;                // scratch in d_out (k4 rewrites all)

  prep_kernel<<<512, 256, 0, stream>>>(w1, w2, wd, woff, ws);
  k1_fused_mfma<<<Bn * 98, 256, 0, stream>>>(x, w1b, b1, g1, be1, m1, v1, out1b);
  k3_deform_mfma<<<Bn * 196, 256, 0, stream>>>(out1b, wofb, boff, wdb, bd,
                                               g2, be2, m2, v2, out2b);
  k4_mfma<<<Bn * 392, 256, 0, stream>>>(out2b, w2b, b2, g3, be3, m3, v3, x, out);
}